// Round 1
// baseline (634.058 us; speedup 1.0000x reference)
//
#include <hip/hip_runtime.h>

#define PI_F 3.14159265358979323846f
#define B_ 8
#define C_ 64
#define H_ 256
#define W_ 512

__device__ __forceinline__ int brev6(int x) { return (int)(__brev((unsigned)x) >> 26); }

// ---------------------------------------------------------------------------
// K3: per-row forward low-band DFT (64 bins of 512) + pooled means.
// One wave per row; lane l holds x[8l..8l+8). F stored (bc, w, h) as float2.
// ---------------------------------------------------------------------------
__global__ __launch_bounds__(256) void krow_fwd(const float* __restrict__ x,
                                                float2* __restrict__ F2,
                                                float* __restrict__ pooled)
{
    const int t = threadIdx.x;
    const int lane = t & 63;
    const int wv = t >> 6;                 // 0..3
    const int bc = blockIdx.x >> 4;        // image index (b*C + c)
    const int h0 = (blockIdx.x & 15) << 4; // 16-row tile

    __shared__ float2 Ft[64][17];

    const int k = brev6(lane);             // my output bin after DIF
    const int kneg = (64 - k) & 63;
    const int lneg = brev6(kneg);          // lane holding bin (64-k)%64
    float b1s, b1c;
    sincosf(-2.0f * PI_F * (float)k / 512.0f, &b1s, &b1c); // u-chain base

    float stc[6], sts[6];                  // DIF stage twiddles e^{-i*pi*j/h}
    #pragma unroll
    for (int s = 0; s < 6; ++s) {
        int hh = 32 >> s;
        int j = lane & (hh - 1);
        sincosf(-PI_F * (float)j / (float)hh, &sts[s], &stc[s]);
    }

    #pragma unroll
    for (int it = 0; it < 4; ++it) {
        const int hl = wv * 4 + it;
        const int h = h0 + hl;
        const float* xr = x + ((size_t)bc * H_ + h) * W_ + lane * 8;
        float4 xa = *(const float4*)(xr);
        float4 xb = *(const float4*)(xr + 4);
        float xs[8] = {xa.x, xa.y, xa.z, xa.w, xb.x, xb.y, xb.z, xb.w};

        // pooled mean of this contiguous block of 8  (j == lane)
        float pm = (xs[0]+xs[1]+xs[2]+xs[3]+xs[4]+xs[5]+xs[6]+xs[7]) * 0.125f;
        pooled[((size_t)bc * H_ + h) * 64 + lane] = pm;

        float Fr = 0.f, Fi = 0.f;
        float tr = 1.f, ti = 0.f;          // e^{-2pi i k u/512}, u = 0,1,2,...
        #pragma unroll
        for (int p = 0; p < 4; ++p) {
            // complex FFT64 across lanes of z = x[8t+2p] + i x[8t+2p+1]
            float zr = xs[2*p], zi = xs[2*p+1];
            #pragma unroll
            for (int s = 0; s < 6; ++s) {
                int hh = 32 >> s;
                float orr = __shfl_xor(zr, hh);
                float oii = __shfl_xor(zi, hh);
                bool up = (lane & hh) != 0;
                float sr = up ? (orr - zr) : (zr + orr);
                float si = up ? (oii - zi) : (zi + oii);
                float mr = sr * stc[s] - si * sts[s];
                float mi = sr * sts[s] + si * stc[s];
                zr = up ? mr : sr;
                zi = up ? mi : si;
            }
            // lane holds Z[k]; split into the two real DFTs
            float znr = __shfl(zr, lneg);
            float zni = __shfl(zi, lneg);
            float Ar = 0.5f * (zr + znr);        // G_{2p}[k]
            float Ai = 0.5f * (zi - zni);
            float Br = 0.5f * (zi + zni);        // G_{2p+1}[k]
            float Bi = 0.5f * (znr - zr);
            Fr += tr * Ar - ti * Ai;
            Fi += tr * Ai + ti * Ar;
            float t2r = tr * b1c - ti * b1s;
            float t2i = tr * b1s + ti * b1c;
            Fr += t2r * Br - t2i * Bi;
            Fi += t2r * Bi + t2i * Br;
            tr = t2r * b1c - t2i * b1s;
            ti = t2r * b1s + t2i * b1c;
        }
        Ft[k][hl] = make_float2(Fr, Fi);
    }
    __syncthreads();
    #pragma unroll
    for (int q = 0; q < 4; ++q) {
        int idx = q * 256 + t;
        int w = idx >> 4;
        int hl = idx & 15;
        F2[((size_t)bc * 64 + w) * H_ + h0 + hl] = Ft[w][hl];
    }
}

// ---------------------------------------------------------------------------
// K2: pooled -> params -> filt; writes g = (filt - 1)/(H*W), layout (b, w, h).
// One block per (b, h). Wave q handles ranks q*8..q*8+7 for all 64 w.
// ---------------------------------------------------------------------------
__global__ __launch_bounds__(256) void kfilt(const float* __restrict__ pooled,
                                             const float* __restrict__ conv_w,
                                             const float* __restrict__ conv_b,
                                             const float* __restrict__ dt,
                                             float2* __restrict__ g2)
{
    const int t = threadIdx.x;
    const int b = blockIdx.x >> 8;
    const int h = blockIdx.x & 255;
    __shared__ float pl[64][65];   // [w][c]
    __shared__ float cw[64][65];   // [o][c]
    __shared__ float red[2][4][64];

    #pragma unroll
    for (int q = 0; q < 16; ++q) {
        int idx = q * 256 + t;
        cw[idx >> 6][idx & 63] = conv_w[idx];
    }
    #pragma unroll
    for (int q = 0; q < 16; ++q) {
        int idx = q * 256 + t;
        int c = idx >> 6, j = idx & 63;
        pl[j][c] = pooled[(((size_t)b * C_ + c) * H_ + h) * 64 + j];
    }
    __syncthreads();

    const int w = t & 63;
    const int q4 = t >> 6;
    const float dtb = dt[b];
    float ar = 0.f, ai = 0.f;
    #pragma unroll
    for (int rr = 0; rr < 8; ++rr) {
        int r = q4 * 8 + rr;
        float d1 = conv_b[r], d2 = conv_b[r + 32];
        #pragma unroll 8
        for (int c = 0; c < 64; ++c) {
            float pv = pl[w][c];
            d1 += pv * cw[r][c];
            d2 += pv * cw[r + 32][c];
        }
        float nu = (d1 > 20.f) ? d1 : log1pf(expf(d1));
        float th = tanhf(d2) * PI_F;
        float dec = expf(-nu * dtb);
        float ang = th * dtb;
        float sa, ca;
        sincosf(ang, &sa, &ca);
        ar += dec * ca;
        ai += dec * sa;
    }
    red[0][q4][w] = ar;
    red[1][q4][w] = ai;
    __syncthreads();
    if (t < 64) {
        float sr = red[0][0][t] + red[0][1][t] + red[0][2][t] + red[0][3][t];
        float si = red[1][0][t] + red[1][1][t] + red[1][2][t] + red[1][3][t];
        const float inv = 1.0f / (float)(H_ * W_);
        g2[((size_t)b * 64 + t) * H_ + h] = make_float2(sr * inv - inv, si * inv);
    }
}

// ---------------------------------------------------------------------------
// K4: per-column 256-pt FFT along H, multiply by g at bit-reversed bins,
// inverse FFT, in place. One wave per column, 4 complex elements per lane.
// ---------------------------------------------------------------------------
__global__ __launch_bounds__(256) void kcol(float2* __restrict__ F2,
                                            const float2* __restrict__ g2)
{
    const int t = threadIdx.x;
    const int lane = t & 63;
    const int wv = t >> 6;
    const int bc = blockIdx.x >> 4;
    const int w = ((blockIdx.x & 15) << 2) + wv;
    const int b = bc / C_;

    float stc[6], sts[6];
    #pragma unroll
    for (int s = 0; s < 6; ++s) {
        int hh = 32 >> s;
        int j = lane & (hh - 1);
        sincosf(-PI_F * (float)j / (float)hh, &sts[s], &stc[s]);
    }
    float t1s, t1c; sincosf(-2.f * PI_F * (float)lane / 256.f, &t1s, &t1c);
    float t2c = t1s, t2s = -t1c;          // t1 * (-i)
    float u1s, u1c; sincosf(-2.f * PI_F * (float)lane / 128.f, &u1s, &u1c);

    float2* base = F2 + ((size_t)bc * 64 + w) * H_;
    float vr[4], vi[4];
    #pragma unroll
    for (int r = 0; r < 4; ++r) {
        float2 val = base[r * 64 + lane];
        vr[r] = val.x; vi[r] = val.y;
    }

    // forward DIF: h=128 (intra), h=64 (intra), h=32..1 (cross-lane)
    {
        float ar = vr[0], ai = vi[0], br = vr[2], bi = vi[2];
        vr[0] = ar + br; vi[0] = ai + bi;
        float dr = ar - br, di = ai - bi;
        vr[2] = dr * t1c - di * t1s; vi[2] = dr * t1s + di * t1c;
        ar = vr[1]; ai = vi[1]; br = vr[3]; bi = vi[3];
        vr[1] = ar + br; vi[1] = ai + bi;
        dr = ar - br; di = ai - bi;
        vr[3] = dr * t2c - di * t2s; vi[3] = dr * t2s + di * t2c;
    }
    {
        float ar = vr[0], ai = vi[0], br = vr[1], bi = vi[1];
        vr[0] = ar + br; vi[0] = ai + bi;
        float dr = ar - br, di = ai - bi;
        vr[1] = dr * u1c - di * u1s; vi[1] = dr * u1s + di * u1c;
        ar = vr[2]; ai = vi[2]; br = vr[3]; bi = vi[3];
        vr[2] = ar + br; vi[2] = ai + bi;
        dr = ar - br; di = ai - bi;
        vr[3] = dr * u1c - di * u1s; vi[3] = dr * u1s + di * u1c;
    }
    #pragma unroll
    for (int s = 0; s < 6; ++s) {
        int hh = 32 >> s;
        #pragma unroll
        for (int r = 0; r < 4; ++r) {
            float orr = __shfl_xor(vr[r], hh);
            float oii = __shfl_xor(vi[r], hh);
            bool up = (lane & hh) != 0;
            float sr = up ? (orr - vr[r]) : (vr[r] + orr);
            float si = up ? (oii - vi[r]) : (vi[r] + oii);
            float mr = sr * stc[s] - si * sts[s];
            float mi = sr * sts[s] + si * stc[s];
            vr[r] = up ? mr : sr;
            vi[r] = up ? mi : si;
        }
    }
    // multiply by g at bin br8(64r+lane) = 4*br6(lane) + br2(r)
    {
        int kb = brev6(lane) * 4;
        const float2* gb = g2 + ((size_t)b * 64 + w) * H_ + kb;
        float2 ga = gb[0], gbv = gb[1], gc = gb[2], gd = gb[3];
        float2 gg[4] = {ga, gc, gbv, gd};   // br2: 0,2,1,3
        #pragma unroll
        for (int r = 0; r < 4; ++r) {
            float nr = vr[r] * gg[r].x - vi[r] * gg[r].y;
            float ni = vr[r] * gg[r].y + vi[r] * gg[r].x;
            vr[r] = nr; vi[r] = ni;
        }
    }
    // inverse DIT: half=1..32 (cross-lane, conj twiddles), 64, 128 (intra)
    #pragma unroll
    for (int s = 0; s < 6; ++s) {
        int hh = 1 << s;
        float wc = stc[5 - s], ws = -sts[5 - s];
        #pragma unroll
        for (int r = 0; r < 4; ++r) {
            float orr = __shfl_xor(vr[r], hh);
            float oii = __shfl_xor(vi[r], hh);
            bool up = (lane & hh) != 0;
            float pr = up ? vr[r] : orr;
            float pi = up ? vi[r] : oii;
            float mwr = pr * wc - pi * ws;
            float mwi = pr * ws + pi * wc;
            float ar = up ? orr : vr[r];
            float ai = up ? oii : vi[r];
            vr[r] = up ? (ar - mwr) : (ar + mwr);
            vi[r] = up ? (ai - mwi) : (ai + mwi);
        }
    }
    {
        float wc = u1c, ws = -u1s;
        float mwr = vr[1]*wc - vi[1]*ws, mwi = vr[1]*ws + vi[1]*wc;
        float ar = vr[0], ai = vi[0];
        vr[0] = ar + mwr; vi[0] = ai + mwi;
        vr[1] = ar - mwr; vi[1] = ai - mwi;
        mwr = vr[3]*wc - vi[3]*ws; mwi = vr[3]*ws + vi[3]*wc;
        ar = vr[2]; ai = vi[2];
        vr[2] = ar + mwr; vi[2] = ai + mwi;
        vr[3] = ar - mwr; vi[3] = ai - mwi;
    }
    {
        float wc = t1c, ws = -t1s;
        float mwr = vr[2]*wc - vi[2]*ws, mwi = vr[2]*ws + vi[2]*wc;
        float ar = vr[0], ai = vi[0];
        vr[0] = ar + mwr; vi[0] = ai + mwi;
        vr[2] = ar - mwr; vi[2] = ai - mwi;
        wc = t2c; ws = -t2s;
        mwr = vr[3]*wc - vi[3]*ws; mwi = vr[3]*ws + vi[3]*wc;
        ar = vr[1]; ai = vi[1];
        vr[1] = ar + mwr; vi[1] = ai + mwi;
        vr[3] = ar - mwr; vi[3] = ai - mwi;
    }
    #pragma unroll
    for (int r = 0; r < 4; ++r)
        base[r * 64 + lane] = make_float2(vr[r], vi[r]);
}

// ---------------------------------------------------------------------------
// K5: inverse low-band row transform + add x -> out. One wave per row.
// ---------------------------------------------------------------------------
__global__ __launch_bounds__(256) void krow_inv(const float2* __restrict__ F2,
                                                const float* __restrict__ x,
                                                float* __restrict__ out)
{
    const int t = threadIdx.x;
    const int lane = t & 63;
    const int wv = t >> 6;
    const int bc = blockIdx.x >> 4;
    const int h0 = (blockIdx.x & 15) << 4;

    __shared__ float2 Dt[64][17];
    #pragma unroll
    for (int q = 0; q < 4; ++q) {
        int idx = q * 256 + t;
        int w = idx >> 4, hl = idx & 15;
        Dt[w][hl] = F2[((size_t)bc * 64 + w) * H_ + h0 + hl];
    }
    __syncthreads();

    const int k = brev6(lane);
    const int kneg = (64 - k) & 63;
    const int lneg = brev6(kneg);
    float b1s, b1c; sincosf(2.f * PI_F * (float)k / 512.f, &b1s, &b1c);
    float stc[6], sts[6];                  // DIT twiddles e^{+i*pi*j/half}
    #pragma unroll
    for (int s = 0; s < 6; ++s) {
        int hh = 1 << s;
        int j = lane & (hh - 1);
        sincosf(PI_F * (float)j / (float)hh, &sts[s], &stc[s]);
    }
    const float eps = (k == 0) ? 1.f : 2.f;

    #pragma unroll
    for (int it = 0; it < 4; ++it) {
        const int hl = wv * 4 + it;
        const int m = h0 + hl;
        float2 D = Dt[k][hl];
        float Dr = D.x * eps, Di = D.y * eps;
        float tr = 1.f, ti = 0.f;
        float o8[8];
        #pragma unroll
        for (int p = 0; p < 4; ++p) {
            float Eur = Dr * tr - Di * ti, Eui = Dr * ti + Di * tr;
            { float nr = tr * b1c - ti * b1s, ni = tr * b1s + ti * b1c; tr = nr; ti = ni; }
            float Evr = Dr * tr - Di * ti, Evi = Dr * ti + Di * tr;
            { float nr = tr * b1c - ti * b1s, ni = tr * b1s + ti * b1c; tr = nr; ti = ni; }
            float Eurn = __shfl(Eur, lneg), Euin = __shfl(Eui, lneg);
            float Evrn = __shfl(Evr, lneg), Evin = __shfl(Evi, lneg);
            float Ahr = 0.5f * (Eur + Eurn), Ahi = 0.5f * (Eui - Euin);
            float Bhr = 0.5f * (Evr + Evrn), Bhi = 0.5f * (Evi - Evin);
            float zr = Ahr - Bhi, zi = Ahi + Bhr;
            #pragma unroll
            for (int s = 0; s < 6; ++s) {
                int hh = 1 << s;
                float orr = __shfl_xor(zr, hh);
                float oii = __shfl_xor(zi, hh);
                bool up = (lane & hh) != 0;
                float pr = up ? zr : orr;
                float pi = up ? zi : oii;
                float mwr = pr * stc[s] - pi * sts[s];
                float mwi = pr * sts[s] + pi * stc[s];
                float ar = up ? orr : zr;
                float ai = up ? oii : zi;
                zr = up ? (ar - mwr) : (ar + mwr);
                zi = up ? (ai - mwi) : (ai + mwi);
            }
            o8[2*p] = zr;
            o8[2*p+1] = zi;
        }
        const float* xr = x + ((size_t)bc * H_ + m) * W_ + lane * 8;
        float* orow = out + ((size_t)bc * H_ + m) * W_ + lane * 8;
        float4 xa = *(const float4*)xr;
        float4 xb = *(const float4*)(xr + 4);
        float4 oa = make_float4(xa.x + o8[0], xa.y + o8[1], xa.z + o8[2], xa.w + o8[3]);
        float4 ob = make_float4(xb.x + o8[4], xb.y + o8[5], xb.z + o8[6], xb.w + o8[7]);
        *(float4*)orow = oa;
        *(float4*)(orow + 4) = ob;
    }
}

extern "C" void kernel_launch(void* const* d_in, const int* in_sizes, int n_in,
                              void* d_out, int out_size, void* d_ws, size_t ws_size,
                              hipStream_t stream)
{
    const float* x      = (const float*)d_in[0];
    const float* dt     = (const float*)d_in[1];
    const float* conv_w = (const float*)d_in[2];
    const float* conv_b = (const float*)d_in[3];
    float* out = (float*)d_out;

    // workspace: F (512*64*256 float2 = 64 MB) | pooled (32 MB) | g (1 MB)
    float2* F2    = (float2*)d_ws;
    float* pooled = (float*)((char*)d_ws + 67108864ull);
    float2* g2    = (float2*)((char*)d_ws + 67108864ull + 33554432ull);

    hipLaunchKernelGGL(krow_fwd, dim3(8192), dim3(256), 0, stream, x, F2, pooled);
    hipLaunchKernelGGL(kfilt,    dim3(2048), dim3(256), 0, stream, pooled, conv_w, conv_b, dt, g2);
    hipLaunchKernelGGL(kcol,     dim3(8192), dim3(256), 0, stream, F2, g2);
    hipLaunchKernelGGL(krow_inv, dim3(8192), dim3(256), 0, stream, F2, x, out);
}